// Round 7
// baseline (172.184 us; speedup 1.0000x reference)
//
#include <hip/hip_runtime.h>
#include <hip/hip_bf16.h>
#include <hip/hip_fp16.h>

// GeneratorSDF: latent-conditioned MLP SDF on a 128^3 grid (fp32 I/O).
// dims: 67 -> 128 -> 64 -> 32 -> 1 (relu, relu, relu, sigmoid)
//
// R29 = R28 (fused dual-rail, 50.0us) + depth-2 register pipeline.
// Ledger: R22 53.5 | R23 57.1 | R24 58.7 | R25 134(spill) | R26 54.1 |
// R27 52.0 | R28 50.0. Only ILP ever paid. Pipes: VALU 44 + MFMA 34 ->
// ~22% idle = residual dependency stalls: (1) pack reads acc in the same
// iter its MFMAs issued; (2) cphase reads zf in the half-body that wrote
// it; (3) pack's ds_writes pinned between bphase consume and prefetch.
// R29 removes all three with ZERO added instructions (R23/R24 invariant):
// pack+write of iter i's groups deferred to iter i+1 (acc live in regs,
// +32 VGPR); half-body order = prefetch -> aphase2(new) -> bphase2(old) ->
// pack(prev-iter); cphase deferred one half-body and placed BEFORE the zf
// overwrite. Explicit E/O half-bodies make every h2-slot / zf index a
// compile-time constant (ds immediate offsets, less addressing VALU).
// Pipeline (pipeline idx i, groups g=2i,2i+1): compute@i (E->a, O->b),
// pack+write@i+1 (E packs b->slots 2,3; O packs a->slots 0,1),
// read+bphase@i+2 (E reads slots 0,1; O reads 2,3). 4 slots, no overlap.
// Pre-committed: null (+-2%) w/o spill => practical structural ceiling.
// Failure: FETCH >> 400KB = spill -> revert R28.
// MFMA layouts (verified m89/m91): A[m=lane&15][k=quad*8+j],
// B[k=quad*8+j][n=lane&15], C/D row=quad*4+reg, col=lane&15.

#define NPTS (128 * 128 * 128)

typedef float f32x4_t __attribute__((ext_vector_type(4)));
typedef float f32x2_t __attribute__((ext_vector_type(2)));
typedef __fp16 g16x2_t __attribute__((ext_vector_type(2)));    // VALU half2 (cvt_pkrtz type)
typedef _Float16 h16x8_t __attribute__((ext_vector_type(8)));  // MFMA fragment

__device__ __forceinline__ unsigned h2u(g16x2_t h) {
    unsigned u;
    __builtin_memcpy(&u, &h, 4);
    return u;
}
__device__ __forceinline__ g16x2_t u2h(unsigned u) {
    g16x2_t h;
    __builtin_memcpy(&h, &u, 4);
    return h;
}

__global__ __launch_bounds__(256, 2) void mlp_kernel(
    const float* __restrict__ x,  const float* __restrict__ W1,
    const float* __restrict__ b1, const float* __restrict__ W2,
    const float* __restrict__ b2, const float* __restrict__ W3,
    const float* __restrict__ b3, const float* __restrict__ W4,
    const float* __restrict__ b4, float* __restrict__ out) {
    __shared__ __align__(16) unsigned s_basep[32][64];  // half2 {base[2c],base[2c+1]} per j
    __shared__ __align__(16) unsigned s_wcp[64];        // half2 wc pairs
    __shared__ __align__(16) float s_b2[64];
    __shared__ __align__(16) float s_b3[32];
    __shared__ __align__(16) float s_w4[32];
    // Union (45 KB): staging = w2a[16][64][8] halves (0..8191) + w3a[4][64][8]
    // (8192..10239) + W1-fold partials (floats at shorts 10240..11263, transient);
    // runtime = h2 slots [w][4][16][72] shorts (0..18431) + zf floats
    // (shorts 18432..22527 = float[4][8][16][4] : w*512 + zi*64 + i*4 + q).
    __shared__ __align__(16) unsigned short s_u[22528];

    const int t = threadIdx.x;
    const int w = t >> 6;
    const int lane = t & 63;
    const int quad = lane >> 4;
    const int l15 = lane & 15;
    const float step = 2.0f / 127.0f;

    // ================= per-block prep, phase 1 (all 256 threads) =============
    // W1 fold partials: thread covers channel-pair p = t&63, c in [h*16,(h+1)*16)
    {
        const int p = t & 63, h = t >> 6;
        const float* r0 = W1 + (2 * p) * 67 + h * 16;
        const float* r1 = r0 + 67;
        const float* xh = x + h * 16;
        float s0 = 0.0f, s1 = 0.0f;
#pragma unroll
        for (int c = 0; c < 16; ++c) {
            const float xc = xh[c];
            s0 = fmaf(r0[c], xc, s0);
            s1 = fmaf(r1[c], xc, s1);
        }
        float2* psum = (float2*)&s_u[10240];   // [h][p], 4 x 64 float2
        psum[h * 64 + p] = make_float2(s0, s1);
    }
    // W2 [64][128] -> f16 A-frag staging (pairs along k)
    const float2* W2v = (const float2*)W2;
#pragma unroll
    for (int it = 0; it < 16; ++it) {
        int pidx = t + 256 * it;
        int idx2 = pidx * 2;
        int o = idx2 >> 7, k = idx2 & 127;
        int mt = o >> 4, lm = o & 15;
        int kb = k >> 5, q = (k >> 3) & 3, jj = k & 7;
        float2 v = W2v[pidx];
        *(unsigned*)&s_u[(mt * 4 + kb) * 512 + (q * 16 + lm) * 8 + jj] =
            h2u(__builtin_amdgcn_cvt_pkrtz(v.x, v.y));
    }
    // W3 [32][64] -> f16 A-frag staging
    const float2* W3v = (const float2*)W3;
#pragma unroll
    for (int it = 0; it < 4; ++it) {
        int pidx = t + 256 * it;
        int idx2 = pidx * 2;
        int o = idx2 >> 6, k = idx2 & 63;
        int mt = o >> 4, lm = o & 15;
        int kb = k >> 5, q = (k >> 3) & 3, jj = k & 7;
        float2 v = W3v[pidx];
        *(unsigned*)&s_u[8192 + (mt * 2 + kb) * 512 + (q * 16 + lm) * 8 + jj] =
            h2u(__builtin_amdgcn_cvt_pkrtz(v.x, v.y));
    }
    if (t < 64) s_b2[t] = b2[t];
    if (t < 32) {
        s_b3[t] = b3[t];
        s_w4[t] = W4[t];
    }
    const float bias4 = b4[0];
    __syncthreads();

    // ================= prep phase 2 (t<64): combine partials + pack tables ====
    // Block covers gi = bid>>2 (a-coord), gj0 = (bid&3)*32 (32 j-rows), all k.
    if (t < 64) {
        const float2* psum = (const float2*)&s_u[10240];
        float2 q0 = psum[t], q1 = psum[64 + t], q2 = psum[128 + t], q3 = psum[192 + t];
        float s0 = b1[2 * t] + (q0.x + q1.x) + (q2.x + q3.x);
        float s1 = b1[2 * t + 1] + (q0.y + q1.y) + (q2.y + q3.y);
        const float* r0 = W1 + (2 * t) * 67;
        const float* r1 = r0 + 67;
        const float pa = -1.0f + step * (float)(blockIdx.x >> 2);   // gi
        const float base0 = fmaf(r0[64], pa, s0);
        const float base1 = fmaf(r1[64], pa, s1);
        const float wb0 = r0[65], wb1 = r1[65];
        const int gj0 = (blockIdx.x & 3) * 32;
        s_wcp[t] = h2u(__builtin_amdgcn_cvt_pkrtz(r0[66], r1[66]));
#pragma unroll
        for (int j = 0; j < 32; ++j) {
            const float pb = -1.0f + step * (float)(gj0 + j);
            s_basep[j][t] = h2u(__builtin_amdgcn_cvt_pkrtz(
                fmaf(wb0, pb, base0), fmaf(wb1, pb, base1)));
        }
    }
    __syncthreads();

    // ================= per-wave fragment preload =================
    h16x8_t a2[16];
#pragma unroll
    for (int f = 0; f < 16; ++f) a2[f] = *(const h16x8_t*)&s_u[f * 512 + lane * 8];
    h16x8_t a3[4];
#pragma unroll
    for (int f = 0; f < 4; ++f) a3[f] = *(const h16x8_t*)&s_u[8192 + f * 512 + lane * 8];
    f32x4_t b2q[4];
#pragma unroll
    for (int mt = 0; mt < 4; ++mt) b2q[mt] = *(const f32x4_t*)&s_b2[mt * 16 + quad * 4];
    f32x4_t b3q[2];
    f32x2_t w4lo[2], w4hi[2];
#pragma unroll
    for (int mt = 0; mt < 2; ++mt) {
        b3q[mt] = *(const f32x4_t*)&s_b3[mt * 16 + quad * 4];
        float4 wq = *(const float4*)&s_w4[mt * 16 + quad * 4];
        w4lo[mt][0] = wq.x; w4lo[mt][1] = wq.y;
        w4hi[mt][0] = wq.z; w4hi[mt][1] = wq.w;
    }
    // wc pairs: loop-invariant, 16 packed regs, pinned
    unsigned twp[16];
#pragma unroll
    for (int kb = 0; kb < 4; ++kb) {
        uint4 v = *(const uint4*)&s_wcp[kb * 16 + quad * 4];
        twp[kb * 4 + 0] = v.x; twp[kb * 4 + 1] = v.y;
        twp[kb * 4 + 2] = v.z; twp[kb * 4 + 3] = v.w;
    }
#pragma unroll
    for (int i = 0; i < 16; ++i) asm volatile("" : "+v"(twp[i]));
    __syncthreads();  // union handoff: staging -> h2/zf scratch

    const int sw = (l15 & 1) * 32;                    // h2 channel swizzle (shorts)
    unsigned short* h2w = &s_u[w * 4608];             // 4 slots x 16 pts x 72 shorts
    unsigned short* h2p = h2w + l15 * 72;             // per-lane point base
    float* zf = (float*)&s_u[18432];                  // [w][zi][i][q]
    const f32x2_t zero2 = {0.0f, 0.0f};
    const g16x2_t zero2h = {(__fp16)0.0f, (__fp16)0.0f};
    const int outbase = blockIdx.x * 4096 + w * 1024;

    // ---- phase bodies (slot/zf indices are call-site constants) ----
    unsigned tbp[16];
    // A-phase x2: layer 1 + layer 2 for local groups pgl, pgl+1
    auto aphase2 = [&](int pgl, f32x4_t accX[4], f32x4_t accY[4]) {
        const float pcX = fmaf(step, (float)((pgl * 16) + l15), -1.0f);
        const float pcY = fmaf(step, (float)(((pgl + 1) * 16) + l15), -1.0f);
        const g16x2_t pc2X = __builtin_amdgcn_cvt_pkrtz(pcX, pcX);
        const g16x2_t pc2Y = __builtin_amdgcn_cvt_pkrtz(pcY, pcY);
        h16x8_t bfX[4], bfY[4];
#pragma unroll
        for (int kb = 0; kb < 4; ++kb) {
            union { h16x8_t v; g16x2_t h[4]; } bx, by;
#pragma unroll
            for (int p = 0; p < 4; ++p) {
                g16x2_t tw = u2h(twp[kb * 4 + p]);
                g16x2_t tb = u2h(tbp[kb * 4 + p]);
                g16x2_t hx = __builtin_elementwise_fma(tw, pc2X, tb);
                g16x2_t hy = __builtin_elementwise_fma(tw, pc2Y, tb);
                bx.h[p] = __builtin_elementwise_max(hx, zero2h);
                by.h[p] = __builtin_elementwise_max(hy, zero2h);
            }
            bfX[kb] = bx.v;
            bfY[kb] = by.v;
        }
#pragma unroll
        for (int mt = 0; mt < 4; ++mt) {
            f32x4_t cX = b2q[mt], cY = b2q[mt];
#pragma unroll
            for (int kb = 0; kb < 4; ++kb) {
                cX = __builtin_amdgcn_mfma_f32_16x16x32_f16(a2[mt * 4 + kb], bfX[kb], cX, 0, 0, 0);
                cY = __builtin_amdgcn_mfma_f32_16x16x32_f16(a2[mt * 4 + kb], bfY[kb], cY, 0, 0, 0);
            }
            accX[mt] = cX;
            accY[mt] = cY;
        }
    };
    // pack + relu + h2 writes for a rail pair into slots s0, s1 (constants)
    auto packstore2 = [&](int s0, int s1, const f32x4_t accX[4], const f32x4_t accY[4]) {
        unsigned short* slotX = h2p + s0 * 1152;
        unsigned short* slotY = h2p + s1 * 1152;
#pragma unroll
        for (int mt = 0; mt < 4; ++mt) {
            g16x2_t loX = __builtin_elementwise_max(
                __builtin_amdgcn_cvt_pkrtz(accX[mt][0], accX[mt][1]), zero2h);
            g16x2_t loY = __builtin_elementwise_max(
                __builtin_amdgcn_cvt_pkrtz(accY[mt][0], accY[mt][1]), zero2h);
            g16x2_t hiX = __builtin_elementwise_max(
                __builtin_amdgcn_cvt_pkrtz(accX[mt][2], accX[mt][3]), zero2h);
            g16x2_t hiY = __builtin_elementwise_max(
                __builtin_amdgcn_cvt_pkrtz(accY[mt][2], accY[mt][3]), zero2h);
            uint2 pkX, pkY;
            pkX.x = h2u(loX); pkX.y = h2u(hiX);
            pkY.x = h2u(loY); pkY.y = h2u(hiY);
            *(uint2*)&slotX[(mt * 16 + quad * 4) ^ sw] = pkX;
            *(uint2*)&slotY[(mt * 16 + quad * 4) ^ sw] = pkY;
        }
    };
    // prefetch b3 B-fragments from slots s0, s1 (constants)
    auto prefetch2 = [&](int s0, int s1, h16x8_t& f0, h16x8_t& f1,
                         h16x8_t& f2, h16x8_t& f3) {
        const unsigned short* ps0 = h2p + s0 * 1152;
        const unsigned short* ps1 = h2p + s1 * 1152;
        f0 = *(const h16x8_t*)&ps0[(0 ^ sw) + quad * 8];
        f1 = *(const h16x8_t*)&ps0[(32 ^ sw) + quad * 8];
        f2 = *(const h16x8_t*)&ps1[(0 ^ sw) + quad * 8];
        f3 = *(const h16x8_t*)&ps1[(32 ^ sw) + quad * 8];
    };
    // B-phase x2: layer 3 + w4-dot; zf indices zi0, zi1 (constants)
    auto bphase2 = [&](int zi0, int zi1, h16x8_t af0, h16x8_t af1,
                       h16x8_t bf0, h16x8_t bf1) {
        f32x2_t zA = zero2, zB = zero2;
#pragma unroll
        for (int mt = 0; mt < 2; ++mt) {
            f32x4_t cA = b3q[mt], cB = b3q[mt];
            cA = __builtin_amdgcn_mfma_f32_16x16x32_f16(a3[mt * 2 + 0], af0, cA, 0, 0, 0);
            cB = __builtin_amdgcn_mfma_f32_16x16x32_f16(a3[mt * 2 + 0], bf0, cB, 0, 0, 0);
            cA = __builtin_amdgcn_mfma_f32_16x16x32_f16(a3[mt * 2 + 1], af1, cA, 0, 0, 0);
            cB = __builtin_amdgcn_mfma_f32_16x16x32_f16(a3[mt * 2 + 1], bf1, cB, 0, 0, 0);
            f32x2_t hA01 = __builtin_elementwise_max((f32x2_t){cA[0], cA[1]}, zero2);
            f32x2_t hB01 = __builtin_elementwise_max((f32x2_t){cB[0], cB[1]}, zero2);
            f32x2_t hA23 = __builtin_elementwise_max((f32x2_t){cA[2], cA[3]}, zero2);
            f32x2_t hB23 = __builtin_elementwise_max((f32x2_t){cB[2], cB[3]}, zero2);
            zA = __builtin_elementwise_fma(w4lo[mt], hA01, zA);
            zB = __builtin_elementwise_fma(w4lo[mt], hB01, zB);
            zA = __builtin_elementwise_fma(w4hi[mt], hA23, zA);
            zB = __builtin_elementwise_fma(w4hi[mt], hB23, zB);
        }
        zf[w * 512 + zi0 * 64 + l15 * 4 + quad] = zA[0] + zA[1];
        zf[w * 512 + zi1 * 64 + l15 * 4 + quad] = zB[0] + zB[1];
    };
    // phase C: batched reduce + sigmoid + coalesced store for an 8-group batch
    auto cphase = [&](int batch) {
#pragma unroll
        for (int half = 0; half < 2; ++half) {
            const int p = lane + 64 * half;   // point within this batch's 128
            const int pg = p >> 4, i = p & 15;
            float4 v = *(const float4*)&zf[w * 512 + pg * 64 + i * 4];
            float z = (v.x + v.y) + (v.z + v.w) + bias4;
            out[outbase + batch * 128 + p] = 1.0f / (1.0f + __expf(-z));
        }
    };

    // pipeline accumulators: 'a' = even-index computes, 'b' = odd-index
    f32x4_t aXa[4], aYa[4], aXb[4], aYb[4];

    // ========== jrow-outer main loop: 8 jrows x 2 E/O body-pairs ==========
    // Wave w owns jrows [w*8, w*8+8). Pipeline index i = jr*4 + 2*pgp2 (+1).
    // compute@i, pack@i+1 (E packs b->slots 2,3 / O packs a->slots 0,1),
    // prefetch+bphase@i+2 (E reads 0,1 / O reads 2,3).
    for (int jr = 0; jr < 8; ++jr) {
        // base pairs for this jrow: 16 packed regs, pinned
        const unsigned* bp = &s_basep[w * 8 + jr][0];
#pragma unroll
        for (int kb = 0; kb < 4; ++kb) {
            uint4 v = *(const uint4*)&bp[kb * 16 + quad * 4];
            tbp[kb * 4 + 0] = v.x; tbp[kb * 4 + 1] = v.y;
            tbp[kb * 4 + 2] = v.z; tbp[kb * 4 + 3] = v.w;
        }
#pragma unroll
        for (int i = 0; i < 16; ++i) asm volatile("" : "+v"(tbp[i]));

#pragma unroll
        for (int pgp2 = 0; pgp2 < 2; ++pgp2) {
            const int iE = jr * 4 + 2 * pgp2;   // even pipeline index
            // ---------- half-body E: compute->a, bphase slots 0,1, pack<-b ----
            {
                const bool doB = (iE >= 2);          // false only at jr=0,pgp2=0
                h16x8_t f0, f1, f2, f3;
                if (doB) prefetch2(0, 1, f0, f1, f2, f3);
                // deferred cphase for batch jr-1: zf written >= one half-body
                // ago; placed BEFORE bphase overwrites zf[0],zf[1].
                if (pgp2 == 1 && jr >= 1) cphase(jr - 1);
                aphase2(4 * pgp2, aXa, aYa);         // groups 2iE, 2iE+1 -> 'a'
                if (doB) bphase2(pgp2 == 0 ? 4 : 0, pgp2 == 0 ? 5 : 1,
                                 f0, f1, f2, f3);    // groups 2iE-4, 2iE-3
                if (doB) packstore2(2, 3, aXb, aYb); // groups 2iE-2, 2iE-1
            }
            // ---------- half-body O: compute->b, bphase slots 2,3, pack<-a ----
            {
                const bool doB = (iE + 1 >= 2);      // false only at jr=0,pgp2=0
                h16x8_t f0, f1, f2, f3;
                if (doB) prefetch2(2, 3, f0, f1, f2, f3);
                aphase2(4 * pgp2 + 2, aXb, aYb);     // groups 2iE+2, 2iE+3 -> 'b'
                if (doB) bphase2(pgp2 == 0 ? 6 : 2, pgp2 == 0 ? 7 : 3,
                                 f0, f1, f2, f3);    // groups 2iE-2, 2iE-1
                packstore2(0, 1, aXa, aYa);          // groups 2iE, 2iE+1
            }
        }
    }
    // ========== drain: i=32 (E-like) and i=33 (O-like) ==========
    {
        h16x8_t f0, f1, f2, f3;
        prefetch2(0, 1, f0, f1, f2, f3);
        bphase2(4, 5, f0, f1, f2, f3);       // groups 60, 61
        packstore2(2, 3, aXb, aYb);          // groups 62, 63
        prefetch2(2, 3, f0, f1, f2, f3);
        bphase2(6, 7, f0, f1, f2, f3);       // groups 62, 63
        cphase(7);
    }
}

extern "C" void kernel_launch(void* const* d_in, const int* in_sizes, int n_in,
                              void* d_out, int out_size, void* d_ws, size_t ws_size,
                              hipStream_t stream) {
    mlp_kernel<<<NPTS / 4096, 256, 0, stream>>>(
        (const float*)d_in[0], (const float*)d_in[1], (const float*)d_in[2],
        (const float*)d_in[3], (const float*)d_in[4], (const float*)d_in[5],
        (const float*)d_in[6], (const float*)d_in[7], (const float*)d_in[8],
        (float*)d_out);
}